// Round 6
// baseline (111.927 us; speedup 1.0000x reference)
//
#include <hip/hip_runtime.h>
#include <math.h>

// Problem constants (from reference)
#define LSEQ   129      // PL + 1
#define PLEN   128
#define NHEAD  8
#define DHEAD  32
#define INNER  256      // NHEAD * V_DIM
#define HID    1024     // 4 * INNER

typedef _Float16 h2 __attribute__((ext_vector_type(2)));
typedef _Float16 h8 __attribute__((ext_vector_type(8)));   // 16 B = 4 VGPRs

__device__ __forceinline__ float fdot2(h2 a, h2 b, float c) {
#if __has_builtin(__builtin_amdgcn_fdot2)
    return __builtin_amdgcn_fdot2(a, b, c, false);   // v_dot2_f32_f16
#else
    return c + (float)a.x * (float)b.x + (float)a.y * (float)b.y;
#endif
}

// 8-element fp16 dot with fp32 accumulate: 4x v_dot2_f32_f16.
__device__ __forceinline__ float dot8(h8 a, h8 b, float c) {
    h2 a0 = __builtin_shufflevector(a, a, 0, 1);
    h2 a1 = __builtin_shufflevector(a, a, 2, 3);
    h2 a2 = __builtin_shufflevector(a, a, 4, 5);
    h2 a3 = __builtin_shufflevector(a, a, 6, 7);
    h2 b0 = __builtin_shufflevector(b, b, 0, 1);
    h2 b1 = __builtin_shufflevector(b, b, 2, 3);
    h2 b2 = __builtin_shufflevector(b, b, 4, 5);
    h2 b3 = __builtin_shufflevector(b, b, 6, 7);
    c = fdot2(a0, b0, c);
    c = fdot2(a1, b1, c);
    c = fdot2(a2, b2, c);
    c = fdot2(a3, b3, c);
    return c;
}

// -------------------------------------------------------------------------
// Kernel 0: repack fp32 weights -> K-oct fp16 (16 B elements) in workspace.
//   W1o[c8*1024 + j]: halves W1[8c8+i][j], i=0..7   (c8<32)
//   W2o[c8*256  + o]: halves W2[8c8+i][o]           (c8<128)
//   Woo[c8*256  + o]: halves Wo[8c8+i][o]           (c8<32)
// -------------------------------------------------------------------------
__global__ __launch_bounds__(256) void repack_kernel(
    const float* __restrict__ W1, const float* __restrict__ W2,
    const float* __restrict__ Wo,
    h8* __restrict__ W1o, h8* __restrict__ W2o, h8* __restrict__ Woo)
{
    int g = blockIdx.x * 256 + threadIdx.x;
    if (g >= 73728) return;
    h8 v;
    if (g < 32768) {                 // W1: c8<32, j<1024
        int c8 = g >> 10, j = g & 1023;
        const float* src = W1 + (8 * c8) * HID + j;
#pragma unroll
        for (int i = 0; i < 8; ++i) v[i] = (_Float16)src[i * HID];
        W1o[g] = v;
    } else if (g < 65536) {          // W2: c8<128, o<256
        int l = g - 32768;
        int c8 = l >> 8, o = l & 255;
        const float* src = W2 + (8 * c8) * INNER + o;
#pragma unroll
        for (int i = 0; i < 8; ++i) v[i] = (_Float16)src[i * INNER];
        W2o[l] = v;
    } else {                         // Wo: c8<32, o<256
        int l = g - 65536;
        int c8 = l >> 8, o = l & 255;
        const float* src = Wo + (8 * c8) * INNER + o;
#pragma unroll
        for (int i = 0; i < 8; ++i) v[i] = (_Float16)src[i * INNER];
        Woo[l] = v;
    }
}

// -------------------------------------------------------------------------
// LDS overlays. Attn tables die before the MLP buffers are born, so they
// share one char array (99 KB). hstat/red live outside the overlay.
// -------------------------------------------------------------------------
struct AttnSmem {                    // 99008 B
    float2 cs[4][16][132];           // [row][j][m]; 132 pad -> 2-way max
    float4 ab[4][8][16];             // (A0,B0,A1,B1) per (row,h,j), scaled
    float2 xp[4][132];               // x pairs; xp[r][0] = emb
    float  sc[4][8][132];            // scores
    int    mk[4][132];               // mask
};
struct MlpSmem {                     // 28672 B
    _Float16 h[4][INNER];            // post-LN
    _Float16 y[4][HID];              // post-ReLU hidden
    _Float16 r[4][INNER];            // residual sum
    float    p[4][4][INNER];         // partials [kc][row][col]
};

// -------------------------------------------------------------------------
// Kernel 1: FUSED. 256 blocks x 1024 threads; block b handles rows
// r0=4b..4b+3. Threads split as 4 groups of 256 (rg = tid>>8); group rg
// runs the algebraically-collapsed attention for row r0+rg (RoPE
// rotation-invariance + rank-2 K/V -> per-(h,j) constants + cos/sin table),
// then all 1024 threads run the MLP (LN -> FF1+ReLU -> FF2 -> +res -> Wo)
// with fp16 K-oct weights + v_dot2_f32_f16. `last` never touches global:
// thread (rg,ch) computes its own residual element in Phase D.
// -------------------------------------------------------------------------
__global__ __launch_bounds__(1024) void fused_kernel(
    const float* __restrict__ x,      // (BN, PL, 2)
    const float* __restrict__ t,      // (BN, L)
    const int*   __restrict__ mask,   // (BN, L)
    const float* __restrict__ emb,    // (2,)
    const float* __restrict__ Wq,     // (2, 256)
    const float* __restrict__ Wk,     // (2, 256)
    const float* __restrict__ Wv,     // (2, 256)
    const float* __restrict__ ln_g,   // (256,)
    const float* __restrict__ ln_b,   // (256,)
    const h8*    __restrict__ W1o,    // (32, 1024) K-octs
    const float* __restrict__ b1,     // (1024,)
    const h8*    __restrict__ W2o,    // (128, 256) K-octs
    const float* __restrict__ b2,     // (256,)
    const h8*    __restrict__ Woo,    // (32, 256)  K-octs
    float*       __restrict__ out)    // (BN, 256)
{
    const int tid = threadIdx.x;      // 0..1023
    const int r0  = blockIdx.x * 4;
    const int rg  = tid >> 8;         // attn row group / MLP k-chunk
    const int ch  = tid & 255;        // channel within row

    __shared__ alignas(16) char smem[sizeof(AttnSmem)];   // 99008 B overlay
    __shared__ float hstat_s[4][8][3];                    // den, S0, S1
    __shared__ float red_s[16][2];                        // LN partials
    AttnSmem* A = reinterpret_cast<AttnSmem*>(smem);
    MlpSmem*  M = reinterpret_cast<MlpSmem*>(smem);

    const int bn = r0 + rg;
    const float* tb = t + bn * LSEQ;
    const float t0  = tb[0];
    const float e0 = emb[0], e1 = emb[1];

    // ---- Phase A: stage x/mask, build cs table and AB table (per group) --
    if (ch < 130) {
        float2 v;
        if (ch == 0)        v = make_float2(e0, e1);
        else if (ch <= 128) v = ((const float2*)(x + bn * PLEN * 2))[ch - 1];
        else                v = make_float2(0.f, 0.f);
        A->xp[rg][ch] = v;
    }
    if (ch < 129) A->mk[rg][ch] = mask[bn * LSEQ + ch];

    for (int i = ch; i < 129 * 16; i += 256) {
        int m = i >> 4, j = i & 15;
        float invf = exp2f(-(float)j * 0.8304820237218407f); // 10000^(-2j/32)
        float sv, cv;
        __sincosf((tb[m] - t0) * invf, &sv, &cv);
        A->cs[rg][j][m] = make_float2(cv, sv);
    }

    if (ch < 128) {
        int h = ch >> 4, j = ch & 15;
        int ce = h * 32 + 2 * j, co = ce + 1;
        float qe = e0 * Wq[ce] + e1 * Wq[256 + ce];
        float qo = e0 * Wq[co] + e1 * Wq[256 + co];
        float k0e = Wk[ce], k0o = Wk[co];
        float k1e = Wk[256 + ce], k1o = Wk[256 + co];
        const float sc = 0.17677669529663687f;   // 1/sqrt(32)
        A->ab[rg][h][j] = make_float4((qe * k0e + qo * k0o) * sc,
                                      (qo * k0e - qe * k0o) * sc,
                                      (qe * k1e + qo * k1o) * sc,
                                      (qo * k1e - qe * k1o) * sc);
    }
    __syncthreads();

    // ---- Phase B: scores. Half-wave per head; lane handles m = l32+32k ---
    const int lane = tid & 63;
    const int wg   = (tid >> 6) & 3;       // wave within group
    const int h    = wg * 2 + (lane >> 5);
    const int l32  = lane & 31;

    {
        float4 ab[16];
#pragma unroll
        for (int j = 0; j < 16; ++j) ab[j] = A->ab[rg][h][j];  // broadcast

#pragma unroll
        for (int k = 0; k < 5; ++k) {
            int m = l32 + 32 * k;
            if (m < 129) {
                float2 xv2 = A->xp[rg][m];
                float accA = 0.f, accB = 0.f;
#pragma unroll
                for (int j = 0; j < 16; ++j) {
                    float2 cs = A->cs[rg][j][m];
                    accA = fmaf(cs.x, ab[j].x, accA);
                    accA = fmaf(cs.y, ab[j].y, accA);
                    accB = fmaf(cs.x, ab[j].z, accB);
                    accB = fmaf(cs.y, ab[j].w, accB);
                }
                A->sc[rg][h][m] = accA * xv2.x + accB * xv2.y;
            }
        }
    }
    __syncthreads();

    // ---- Phase C: per-head softmax + S0/S1 (reduce over 32 lanes) ----
    {
        const int mask0 = A->mk[rg][0];
        float se[5];
        float Mx = -1e30f;
#pragma unroll
        for (int k = 0; k < 5; ++k) {
            int m = l32 + 32 * k;
            float s;
            if (m < 129) {
                s = A->sc[rg][h][m];
                if (mask0 == 0)            s = 0.f;     // all masked: uniform
                else if (A->mk[rg][m] == 0) s = -1e9f;  // exp underflows to 0
            } else s = -1e30f;
            se[k] = s;
            Mx = fmaxf(Mx, s);
        }
#pragma unroll
        for (int off = 16; off >= 1; off >>= 1)
            Mx = fmaxf(Mx, __shfl_xor(Mx, off, 64));

        float den = 0.f, S0 = 0.f, S1 = 0.f;
#pragma unroll
        for (int k = 0; k < 5; ++k) {
            int m = l32 + 32 * k;
            if (m < 129) {
                float e = __expf(se[k] - Mx);
                float2 xv2 = A->xp[rg][m];
                den += e;
                S0 = fmaf(e, xv2.x, S0);
                S1 = fmaf(e, xv2.y, S1);
            }
        }
#pragma unroll
        for (int off = 16; off >= 1; off >>= 1) {
            den += __shfl_xor(den, off, 64);
            S0  += __shfl_xor(S0,  off, 64);
            S1  += __shfl_xor(S1,  off, 64);
        }
        if (l32 == 0) {
            hstat_s[rg][h][0] = den;
            hstat_s[rg][h][1] = S0;
            hstat_s[rg][h][2] = S1;
        }
    }
    __syncthreads();   // attn overlay dead from here on

    // ---- Phase D: ctx via rank-2 V -> last element stays in register ----
    float xv;   // last[r0+rg][ch]
    {
        int hh = ch >> 5;
        float inv = 1.f / hstat_s[rg][hh][0];
        xv = (hstat_s[rg][hh][1] * Wv[ch] +
              hstat_s[rg][hh][2] * Wv[256 + ch]) * inv;
    }

    // ---- LayerNorm (row rg spans waves 4rg..4rg+3) ----
    {
        float s1 = xv, s2 = xv * xv;
#pragma unroll
        for (int off = 32; off >= 1; off >>= 1) {
            s1 += __shfl_xor(s1, off, 64);
            s2 += __shfl_xor(s2, off, 64);
        }
        const int wave = tid >> 6;
        if ((tid & 63) == 0) { red_s[wave][0] = s1; red_s[wave][1] = s2; }
    }
    __syncthreads();
    {
        float t1 = red_s[4 * rg + 0][0] + red_s[4 * rg + 1][0] +
                   red_s[4 * rg + 2][0] + red_s[4 * rg + 3][0];
        float t2 = red_s[4 * rg + 0][1] + red_s[4 * rg + 1][1] +
                   red_s[4 * rg + 2][1] + red_s[4 * rg + 3][1];
        float mu  = t1 * (1.f / 256.f);
        float var = t2 * (1.f / 256.f) - mu * mu;
        float rs  = rsqrtf(var + 1e-5f);
        M->h[rg][ch] = (_Float16)((xv - mu) * rs * ln_g[ch] + ln_b[ch]);
    }
    __syncthreads();

    // ---- FF1: thread owns hidden col tid; 4 row-accumulators ----
    {
        float a0, a1v, a2v, a3;
        a0 = a1v = a2v = a3 = b1[tid];
        const h8* w = W1o + tid;
#pragma unroll 8
        for (int c8 = 0; c8 < 32; ++c8) {
            h8 wv = w[c8 * HID];
            h8 h0 = *(const h8*)&M->h[0][c8 * 8];
            h8 h1 = *(const h8*)&M->h[1][c8 * 8];
            h8 hh2 = *(const h8*)&M->h[2][c8 * 8];
            h8 h3 = *(const h8*)&M->h[3][c8 * 8];
            a0  = dot8(h0, wv, a0);
            a1v = dot8(h1, wv, a1v);
            a2v = dot8(hh2, wv, a2v);
            a3  = dot8(h3, wv, a3);
        }
        M->y[0][tid] = (_Float16)fmaxf(a0, 0.f);
        M->y[1][tid] = (_Float16)fmaxf(a1v, 0.f);
        M->y[2][tid] = (_Float16)fmaxf(a2v, 0.f);
        M->y[3][tid] = (_Float16)fmaxf(a3, 0.f);
    }
    __syncthreads();

    // ---- FF2: thread (kc=rg, col=ch), K-chunk of 32 octs; 4 rows ----
    {
        float a0 = 0.f, a1v = 0.f, a2v = 0.f, a3 = 0.f;
        const h8* w = W2o + rg * 32 * INNER + ch;
#pragma unroll 8
        for (int i = 0; i < 32; ++i) {
            int c8 = rg * 32 + i;
            h8 wv = w[i * INNER];
            h8 y0 = *(const h8*)&M->y[0][c8 * 8];
            h8 y1 = *(const h8*)&M->y[1][c8 * 8];
            h8 y2 = *(const h8*)&M->y[2][c8 * 8];
            h8 y3 = *(const h8*)&M->y[3][c8 * 8];
            a0  = dot8(y0, wv, a0);
            a1v = dot8(y1, wv, a1v);
            a2v = dot8(y2, wv, a2v);
            a3  = dot8(y3, wv, a3);
        }
        M->p[rg][0][ch] = a0;
        M->p[rg][1][ch] = a1v;
        M->p[rg][2][ch] = a2v;
        M->p[rg][3][ch] = a3;
    }
    __syncthreads();

    // ---- combine + bias + residual (fp32), repack to fp16 ----
    {
        float rv = xv + b2[ch] +
                   M->p[0][rg][ch] + M->p[1][rg][ch] +
                   M->p[2][rg][ch] + M->p[3][rg][ch];
        M->r[rg][ch] = (_Float16)rv;
    }
    __syncthreads();

    // ---- Wo: thread (kc=rg, col=ch), K-chunk of 8 octs; 4 rows ----
    {
        float a0 = 0.f, a1v = 0.f, a2v = 0.f, a3 = 0.f;
        const h8* w = Woo + rg * 8 * INNER + ch;
#pragma unroll
        for (int i = 0; i < 8; ++i) {
            int c8 = rg * 8 + i;
            h8 wv = w[i * INNER];
            h8 v0 = *(const h8*)&M->r[0][c8 * 8];
            h8 v1 = *(const h8*)&M->r[1][c8 * 8];
            h8 v2 = *(const h8*)&M->r[2][c8 * 8];
            h8 v3 = *(const h8*)&M->r[3][c8 * 8];
            a0  = dot8(v0, wv, a0);
            a1v = dot8(v1, wv, a1v);
            a2v = dot8(v2, wv, a2v);
            a3  = dot8(v3, wv, a3);
        }
        M->p[rg][0][ch] = a0;
        M->p[rg][1][ch] = a1v;
        M->p[rg][2][ch] = a2v;
        M->p[rg][3][ch] = a3;
    }
    __syncthreads();

    out[(r0 + rg) * INNER + ch] = M->p[0][rg][ch] + M->p[1][rg][ch] +
                                  M->p[2][rg][ch] + M->p[3][rg][ch];
}

// -------------------------------------------------------------------------
extern "C" void kernel_launch(void* const* d_in, const int* in_sizes, int n_in,
                              void* d_out, int out_size, void* d_ws, size_t ws_size,
                              hipStream_t stream) {
    const float* x    = (const float*)d_in[0];
    const float* t    = (const float*)d_in[1];
    const int*   mask = (const int*)  d_in[2];
    const float* emb  = (const float*)d_in[3];
    const float* Wq   = (const float*)d_in[4];
    const float* Wk   = (const float*)d_in[5];
    const float* Wv   = (const float*)d_in[6];
    const float* Wo   = (const float*)d_in[7];
    const float* ln_g = (const float*)d_in[8];
    const float* ln_b = (const float*)d_in[9];
    const float* W1   = (const float*)d_in[10];
    const float* b1   = (const float*)d_in[11];
    const float* W2   = (const float*)d_in[12];
    const float* b2   = (const float*)d_in[13];
    float* out = (float*)d_out;

    const int BN = in_sizes[1] / LSEQ;   // 1024

    char* ws = (char*)d_ws;
    h8* W1o = (h8*)ws;                       // 512 KB (32768 x 16 B)
    h8* W2o = (h8*)(ws + (512u << 10));      // 512 KB
    h8* Woo = (h8*)(ws + (1u << 20));        // 128 KB

    repack_kernel<<<288, 256, 0, stream>>>(W1, W2, Wo, W1o, W2o, Woo);
    fused_kernel<<<BN / 4, 1024, 0, stream>>>(x, t, mask, emb, Wq, Wk, Wv,
                                              ln_g, ln_b, W1o, b1, W2o, b2,
                                              Woo, out);
}

// Round 7
// 107.416 us; speedup vs baseline: 1.0420x; 1.0420x over previous
//
#include <hip/hip_runtime.h>
#include <math.h>

// Problem constants (from reference)
#define LSEQ   129      // PL + 1
#define PLEN   128
#define NHEAD  8
#define DHEAD  32
#define INNER  256      // NHEAD * V_DIM
#define HID    1024     // 4 * INNER

typedef _Float16 h2 __attribute__((ext_vector_type(2)));
typedef _Float16 h8 __attribute__((ext_vector_type(8)));   // 16 B = 4 VGPRs

__device__ __forceinline__ float fdot2(h2 a, h2 b, float c) {
#if __has_builtin(__builtin_amdgcn_fdot2)
    return __builtin_amdgcn_fdot2(a, b, c, false);   // v_dot2_f32_f16
#else
    return c + (float)a.x * (float)b.x + (float)a.y * (float)b.y;
#endif
}

// 8-element fp16 dot with fp32 accumulate: 4x v_dot2_f32_f16.
__device__ __forceinline__ float dot8(h8 a, h8 b, float c) {
    h2 a0 = __builtin_shufflevector(a, a, 0, 1);
    h2 a1 = __builtin_shufflevector(a, a, 2, 3);
    h2 a2 = __builtin_shufflevector(a, a, 4, 5);
    h2 a3 = __builtin_shufflevector(a, a, 6, 7);
    h2 b0 = __builtin_shufflevector(b, b, 0, 1);
    h2 b1 = __builtin_shufflevector(b, b, 2, 3);
    h2 b2 = __builtin_shufflevector(b, b, 4, 5);
    h2 b3 = __builtin_shufflevector(b, b, 6, 7);
    c = fdot2(a0, b0, c);
    c = fdot2(a1, b1, c);
    c = fdot2(a2, b2, c);
    c = fdot2(a3, b3, c);
    return c;
}

// -------------------------------------------------------------------------
// Kernel 1: single-query (l=0) attention (algebraically collapsed) PLUS
// weight repack prologue (fp32 -> K-oct fp16, 16 B elements).
//
// Repack layouts (K-major octs, columns contiguous for coalescing):
//   W1o[c8*1024 + j]: halves W1[8c8+i][j], i=0..7   (c8<32)
//   W2o[c8*256  + o]: halves W2[8c8+i][o]           (c8<128)
//   Woo[c8*256  + o]: halves Wo[8c8+i][o]           (c8<32)
// 73728 pack items over 1024x256 threads: blocks 0..287 do one item each.
//
// Attention identity (RoPE rotation-invariance + rank-2 K/V):
//   score[h,m] = x0_m*sum_j(c*A0+s*B0) + x1_m*sum_j(c*A1+s*B1),
//   D=(t_m-t_0)*invf_j;  ctx[h,d] = (S0_h*wv0 + S1_h*wv1)/den_h.
// NOTE (r6 post-mortem): do NOT fuse this with the MLP kernel — fusion
// forces 1 block/CU (99 KB LDS) and serializes 4 rows behind shared
// barriers; measured +3.9 us vs this 2-kernel structure.
// -------------------------------------------------------------------------
__global__ __launch_bounds__(256) void attn_kernel(
    const float* __restrict__ x,      // (BN, PL, 2)
    const float* __restrict__ t,      // (BN, L)
    const int*   __restrict__ mask,   // (BN, L)
    const float* __restrict__ emb,    // (2,)
    const float* __restrict__ Wq,     // (2, 256)
    const float* __restrict__ Wk,     // (2, 256)
    const float* __restrict__ Wv,     // (2, 256)
    const float* __restrict__ W1,     // (256, 1024)
    const float* __restrict__ W2,     // (1024, 256)
    const float* __restrict__ Wo,     // (256, 256)
    float*       __restrict__ last,   // (BN, 256)
    h8*          __restrict__ W1o,
    h8*          __restrict__ W2o,
    h8*          __restrict__ Woo)
{
    const int bn  = blockIdx.x;
    const int tid = threadIdx.x;

    // ---- Weight repack prologue (independent of LDS phases) ----
    {
        int g = bn * 256 + tid;
        if (g < 73728) {
            h8 v;
            if (g < 32768) {                 // W1: c8<32, j<1024
                int c8 = g >> 10, j = g & 1023;
                const float* src = W1 + (8 * c8) * HID + j;
#pragma unroll
                for (int i = 0; i < 8; ++i) v[i] = (_Float16)src[i * HID];
                W1o[g] = v;
            } else if (g < 65536) {          // W2: c8<128, o<256
                int l = g - 32768;
                int c8 = l >> 8, o = l & 255;
                const float* src = W2 + (8 * c8) * INNER + o;
#pragma unroll
                for (int i = 0; i < 8; ++i) v[i] = (_Float16)src[i * INNER];
                W2o[l] = v;
            } else {                         // Wo: c8<32, o<256
                int l = g - 65536;
                int c8 = l >> 8, o = l & 255;
                const float* src = Wo + (8 * c8) * INNER + o;
#pragma unroll
                for (int i = 0; i < 8; ++i) v[i] = (_Float16)src[i * INNER];
                Woo[l] = v;
            }
        }
    }

    __shared__ float2 cs_s[16][132];   // [j][m]; 132 pad -> 2-way max
    __shared__ float2 x_s[132];        // x pairs; x_s[0] = emb
    __shared__ float4 ab_s[8][16];     // (A0,B0,A1,B1) per (h,j), scaled
    __shared__ float  sc_s[8][132];    // scores
    __shared__ int    mask_s[132];
    __shared__ float  hstat_s[8][3];   // den, S0, S1 per head

    const float* tb = t + bn * LSEQ;
    const float t0  = tb[0];
    const float e0 = emb[0], e1 = emb[1];

    // ---- Phase A: stage x/mask, build cs table and AB table ----
    if (tid < 130) {
        float2 v;
        if (tid == 0)        v = make_float2(e0, e1);
        else if (tid <= 128) v = ((const float2*)(x + bn * PLEN * 2))[tid - 1];
        else                 v = make_float2(0.f, 0.f);
        x_s[tid] = v;
    }
    if (tid < 129) mask_s[tid] = mask[bn * LSEQ + tid];

    for (int i = tid; i < 129 * 16; i += 256) {
        int m = i >> 4, j = i & 15;
        float invf = exp2f(-(float)j * 0.8304820237218407f); // 10000^(-2j/32)
        float sv, cv;
        __sincosf((tb[m] - t0) * invf, &sv, &cv);
        cs_s[j][m] = make_float2(cv, sv);
    }

    if (tid < 128) {
        int h = tid >> 4, j = tid & 15;
        int ce = h * 32 + 2 * j, co = ce + 1;
        float qe = e0 * Wq[ce] + e1 * Wq[256 + ce];
        float qo = e0 * Wq[co] + e1 * Wq[256 + co];
        float k0e = Wk[ce], k0o = Wk[co];
        float k1e = Wk[256 + ce], k1o = Wk[256 + co];
        const float sc = 0.17677669529663687f;   // 1/sqrt(32)
        ab_s[h][j] = make_float4((qe * k0e + qo * k0o) * sc,
                                 (qo * k0e - qe * k0o) * sc,
                                 (qe * k1e + qo * k1o) * sc,
                                 (qo * k1e - qe * k1o) * sc);
    }
    __syncthreads();

    // ---- Phase B: scores. Half-wave per head; lane handles m = l32+32k ----
    const int lane = tid & 63;
    const int wv   = tid >> 6;
    const int h    = wv * 2 + (lane >> 5);
    const int l32  = lane & 31;

    float4 ab[16];
#pragma unroll
    for (int j = 0; j < 16; ++j) ab[j] = ab_s[h][j];  // broadcast reads

#pragma unroll
    for (int k = 0; k < 5; ++k) {
        int m = l32 + 32 * k;
        if (m < 129) {
            float2 xv = x_s[m];
            float accA = 0.f, accB = 0.f;
#pragma unroll
            for (int j = 0; j < 16; ++j) {
                float2 cs = cs_s[j][m];
                accA = fmaf(cs.x, ab[j].x, accA);
                accA = fmaf(cs.y, ab[j].y, accA);
                accB = fmaf(cs.x, ab[j].z, accB);
                accB = fmaf(cs.y, ab[j].w, accB);
            }
            sc_s[h][m] = accA * xv.x + accB * xv.y;
        }
    }
    __syncthreads();

    // ---- Phase C: per-head softmax + S0/S1 (reduce over 32 lanes) ----
    const int mask0 = mask_s[0];
    float se[5];
    float M = -1e30f;
#pragma unroll
    for (int k = 0; k < 5; ++k) {
        int m = l32 + 32 * k;
        float s;
        if (m < 129) {
            s = sc_s[h][m];
            if (mask0 == 0)          s = 0.f;     // all masked -> uniform
            else if (mask_s[m] == 0) s = -1e9f;   // exp underflows to 0
        } else s = -1e30f;
        se[k] = s;
        M = fmaxf(M, s);
    }
#pragma unroll
    for (int off = 16; off >= 1; off >>= 1) M = fmaxf(M, __shfl_xor(M, off, 64));

    float den = 0.f, S0 = 0.f, S1 = 0.f;
#pragma unroll
    for (int k = 0; k < 5; ++k) {
        int m = l32 + 32 * k;
        if (m < 129) {
            float e = __expf(se[k] - M);
            float2 xv = x_s[m];
            den += e;
            S0 = fmaf(e, xv.x, S0);
            S1 = fmaf(e, xv.y, S1);
        }
    }
#pragma unroll
    for (int off = 16; off >= 1; off >>= 1) {
        den += __shfl_xor(den, off, 64);
        S0  += __shfl_xor(S0,  off, 64);
        S1  += __shfl_xor(S1,  off, 64);
    }
    if (l32 == 0) {
        hstat_s[h][0] = den; hstat_s[h][1] = S0; hstat_s[h][2] = S1;
    }
    __syncthreads();

    // ---- Phase D: ctx via rank-2 V ----
    {
        int hh = tid >> 5;
        float inv = 1.f / hstat_s[hh][0];
        last[bn * 256 + tid] =
            (hstat_s[hh][1] * Wv[tid] + hstat_s[hh][2] * Wv[256 + tid]) * inv;
    }
}

// -------------------------------------------------------------------------
// Kernel 2: LayerNorm -> FF1(256->1024)+ReLU -> FF2(1024->256) -> +residual
//           -> Wo (256->256). 4 rows/block, 1024 threads. K-oct fp16
//           weights (dwordx4 loads), activations staged as contiguous fp16
//           rows read via wave-uniform ds_read_b128 (broadcast, no bank
//           conflicts). Residual kept in register (same thread produces
//           and consumes last[r0+rg][ch]).
// -------------------------------------------------------------------------
__global__ __launch_bounds__(1024) void mlp_kernel(
    const float* __restrict__ last,  // (BN, 256)
    const float* __restrict__ ln_g,  // (256,)
    const float* __restrict__ ln_b,  // (256,)
    const h8*    __restrict__ W1o,   // (32, 1024) K-octs
    const float* __restrict__ b1,    // (1024,)
    const h8*    __restrict__ W2o,   // (128, 256) K-octs
    const float* __restrict__ b2,    // (256,)
    const h8*    __restrict__ Woo,   // (32, 256)  K-octs
    float*       __restrict__ out)   // (BN, 256)
{
    const int tid = threadIdx.x;      // 0..1023
    const int r0  = blockIdx.x * 4;
    const int rg  = tid >> 8;         // row (LN) / k-chunk (FF2, Wo)
    const int ch  = tid & 255;

    __shared__ alignas(16) _Float16 h_h[4][INNER];   //  2 KB post-LN
    __shared__ alignas(16) _Float16 y_h[4][HID];     //  8 KB post-ReLU
    __shared__ alignas(16) _Float16 r_h[4][INNER];   //  2 KB residual
    __shared__ float p_s[4][4][INNER];               // 16 KB partials
    __shared__ float red_s[16][2];

    // ---- load 4 rows (thread keeps its residual element in register) ----
    float xv = last[(r0 + rg) * INNER + ch];

    // ---- LayerNorm (row rg spans waves 4rg..4rg+3) ----
    float s1 = xv, s2 = xv * xv;
#pragma unroll
    for (int off = 32; off >= 1; off >>= 1) {
        s1 += __shfl_xor(s1, off, 64);
        s2 += __shfl_xor(s2, off, 64);
    }
    const int wave = tid >> 6;
    if ((tid & 63) == 0) { red_s[wave][0] = s1; red_s[wave][1] = s2; }
    __syncthreads();

    {
        float t1 = red_s[4 * rg + 0][0] + red_s[4 * rg + 1][0] +
                   red_s[4 * rg + 2][0] + red_s[4 * rg + 3][0];
        float t2 = red_s[4 * rg + 0][1] + red_s[4 * rg + 1][1] +
                   red_s[4 * rg + 2][1] + red_s[4 * rg + 3][1];
        float mu  = t1 * (1.f / 256.f);
        float var = t2 * (1.f / 256.f) - mu * mu;
        float rs  = rsqrtf(var + 1e-5f);
        h_h[rg][ch] = (_Float16)((xv - mu) * rs * ln_g[ch] + ln_b[ch]);
    }
    __syncthreads();

    // ---- FF1: thread owns hidden col tid; 4 row-accumulators ----
    {
        float a0, a1v, a2v, a3;
        a0 = a1v = a2v = a3 = b1[tid];
        const h8* w = W1o + tid;
#pragma unroll 8
        for (int c8 = 0; c8 < 32; ++c8) {
            h8 wv = w[c8 * HID];
            h8 h0 = *(const h8*)&h_h[0][c8 * 8];
            h8 h1 = *(const h8*)&h_h[1][c8 * 8];
            h8 hh2 = *(const h8*)&h_h[2][c8 * 8];
            h8 h3 = *(const h8*)&h_h[3][c8 * 8];
            a0  = dot8(h0, wv, a0);
            a1v = dot8(h1, wv, a1v);
            a2v = dot8(hh2, wv, a2v);
            a3  = dot8(h3, wv, a3);
        }
        y_h[0][tid] = (_Float16)fmaxf(a0, 0.f);
        y_h[1][tid] = (_Float16)fmaxf(a1v, 0.f);
        y_h[2][tid] = (_Float16)fmaxf(a2v, 0.f);
        y_h[3][tid] = (_Float16)fmaxf(a3, 0.f);
    }
    __syncthreads();

    // ---- FF2: thread (kc=rg, col=ch), K-chunk of 32 octs; 4 rows ----
    {
        float a0 = 0.f, a1v = 0.f, a2v = 0.f, a3 = 0.f;
        const h8* w = W2o + rg * 32 * INNER + ch;
#pragma unroll 8
        for (int i = 0; i < 32; ++i) {
            int c8 = rg * 32 + i;
            h8 wv = w[i * INNER];
            h8 y0 = *(const h8*)&y_h[0][c8 * 8];
            h8 y1 = *(const h8*)&y_h[1][c8 * 8];
            h8 y2 = *(const h8*)&y_h[2][c8 * 8];
            h8 y3 = *(const h8*)&y_h[3][c8 * 8];
            a0  = dot8(y0, wv, a0);
            a1v = dot8(y1, wv, a1v);
            a2v = dot8(y2, wv, a2v);
            a3  = dot8(y3, wv, a3);
        }
        p_s[rg][0][ch] = a0;
        p_s[rg][1][ch] = a1v;
        p_s[rg][2][ch] = a2v;
        p_s[rg][3][ch] = a3;
    }
    __syncthreads();

    // ---- combine + bias + residual (fp32), repack to fp16 ----
    {
        float rv = xv + b2[ch] +
                   p_s[0][rg][ch] + p_s[1][rg][ch] +
                   p_s[2][rg][ch] + p_s[3][rg][ch];
        r_h[rg][ch] = (_Float16)rv;
    }
    __syncthreads();

    // ---- Wo: thread (kc=rg, col=ch), K-chunk of 8 octs; 4 rows ----
    {
        float a0 = 0.f, a1v = 0.f, a2v = 0.f, a3 = 0.f;
        const h8* w = Woo + rg * 8 * INNER + ch;
#pragma unroll
        for (int i = 0; i < 8; ++i) {
            int c8 = rg * 8 + i;
            h8 wv = w[i * INNER];
            h8 v0 = *(const h8*)&r_h[0][c8 * 8];
            h8 v1 = *(const h8*)&r_h[1][c8 * 8];
            h8 v2 = *(const h8*)&r_h[2][c8 * 8];
            h8 v3 = *(const h8*)&r_h[3][c8 * 8];
            a0  = dot8(v0, wv, a0);
            a1v = dot8(v1, wv, a1v);
            a2v = dot8(v2, wv, a2v);
            a3  = dot8(v3, wv, a3);
        }
        p_s[rg][0][ch] = a0;
        p_s[rg][1][ch] = a1v;
        p_s[rg][2][ch] = a2v;
        p_s[rg][3][ch] = a3;
    }
    __syncthreads();

    out[(r0 + rg) * INNER + ch] = p_s[0][rg][ch] + p_s[1][rg][ch] +
                                  p_s[2][rg][ch] + p_s[3][rg][ch];
}

// -------------------------------------------------------------------------
extern "C" void kernel_launch(void* const* d_in, const int* in_sizes, int n_in,
                              void* d_out, int out_size, void* d_ws, size_t ws_size,
                              hipStream_t stream) {
    const float* x    = (const float*)d_in[0];
    const float* t    = (const float*)d_in[1];
    const int*   mask = (const int*)  d_in[2];
    const float* emb  = (const float*)d_in[3];
    const float* Wq   = (const float*)d_in[4];
    const float* Wk   = (const float*)d_in[5];
    const float* Wv   = (const float*)d_in[6];
    const float* Wo   = (const float*)d_in[7];
    const float* ln_g = (const float*)d_in[8];
    const float* ln_b = (const float*)d_in[9];
    const float* W1   = (const float*)d_in[10];
    const float* b1   = (const float*)d_in[11];
    const float* W2   = (const float*)d_in[12];
    const float* b2   = (const float*)d_in[13];
    float* out = (float*)d_out;

    const int BN = in_sizes[1] / LSEQ;   // 1024

    char* ws = (char*)d_ws;
    float* last_ws = (float*)ws;             // 1 MB
    h8* W1o = (h8*)(ws + (1u << 20));        // 512 KB (32768 x 16 B)
    h8* W2o = (h8*)(ws + (1u << 20) + (512u << 10));   // 512 KB
    h8* Woo = (h8*)(ws + (2u << 20));        // 128 KB

    attn_kernel<<<BN, 256, 0, stream>>>(x, t, mask, emb, Wq, Wk, Wv,
                                        W1, W2, Wo, last_ws, W1o, W2o, Woo);
    mlp_kernel<<<BN / 4, 1024, 0, stream>>>(last_ws, ln_g, ln_b, W1o, b1,
                                            W2o, b2, Woo, out);
}